// Round 11
// baseline (63.004 us; speedup 1.0000x reference)
//
#include <hip/hip_runtime.h>

// out[b,o] = (rowsum(x)[b] + rowsum(w)[o]) * bias[o]
// B=8192, IN=2048, OUT=2048, all float32.
//
// ONE fused kernel + 8-KB sentinel memset. Sync = sentinel-poll on the data
// (R10, worked); R11 fixes the wave-starvation R10's rocprof exposed
// (512 blocks = 8 waves/CU -> 2.75 TB/s; stores need no latency hiding but
// reads do). Now 2048 blocks x 256 @ __launch_bounds__(256,8):
// 8 blocks/CU x 256 CU = 2048 slots >= grid -> all blocks resident, and
// every block PRODUCES (wave 0: w-row blk) before it POLLS -> deadlock-free.
// No atomic RMW, no fences (R5/R8/R9 lessons: same-line RMW arrivals
// serialize ~30ns each; per-thread agent fences are cache-op storms).

#define B_DIM 8192
#define IN_DIM 2048
#define OUT_DIM 2048
#define NBLK 2048
#define SENT 0xFFFFFFFFu

typedef float f32x4 __attribute__((ext_vector_type(4)));

__device__ __forceinline__ float butterfly_reduce(float s) {
    #pragma unroll
    for (int off = 32; off; off >>= 1)
        s += __shfl_xor(s, off, 64);
    return s;   // result in all 64 lanes
}

__device__ __forceinline__ float row_reduce(const float* __restrict__ row, int lane) {
    const f32x4* r4 = reinterpret_cast<const f32x4*>(row);
    f32x4 v[8];
    #pragma unroll
    for (int k = 0; k < 8; ++k)
        v[k] = r4[lane + (k << 6)];
    float s = 0.f;
    #pragma unroll
    for (int k = 0; k < 8; ++k)
        s += (v[k].x + v[k].y) + (v[k].z + v[k].w);
    return butterfly_reduce(s);
}

__global__ __launch_bounds__(256, 8) void fused_all(const float* __restrict__ x,
                                                    const float* __restrict__ w,
                                                    const float* __restrict__ bias,
                                                    float* __restrict__ out,
                                                    float* __restrict__ wsb) {
    const int tid  = threadIdx.x;
    const int wave = tid >> 6;
    const int lane = tid & 63;
    const int blk  = blockIdx.x;               // 0 .. 2047

    // ---- phase 1: wave 0 reduces w-row `blk`, publishes write-through ----
    if (wave == 0) {
        float s = row_reduce(w + (size_t)blk * IN_DIM, lane);
        if (lane == 0)
            __hip_atomic_store(&wsb[blk], s * bias[blk],
                               __ATOMIC_RELAXED, __HIP_MEMORY_SCOPE_AGENT);
    }

    // ---- phase 2: each wave reduces one x-row ----
    const int xrow = (blk << 2) + wave;        // 0 .. 8191
    const float xs = row_reduce(x + (size_t)xrow * IN_DIM, lane);

    // ---- sync: block-cooperative sentinel poll (expected 1 iteration) ----
    const unsigned* wsb_u = reinterpret_cast<const unsigned*>(wsb);
    int ok;
    do {
        ok = 1;
        #pragma unroll
        for (int m = 0; m < 8; ++m) {
            unsigned u = __hip_atomic_load(&wsb_u[tid + (m << 8)],
                                           __ATOMIC_RELAXED,
                                           __HIP_MEMORY_SCOPE_AGENT);
            ok &= (u != SENT);
        }
        if (!ok) __builtin_amdgcn_s_sleep(8);
    } while (!__syncthreads_and(ok));

    // ---- phase 3: each wave writes its out-row (plain cached loads, safe:
    //      dispatch-start invalidate killed pre-kernel lines; in-kernel lines
    //      only arise from post-confirmation loads) ----
    const f32x4* bias4 = reinterpret_cast<const f32x4*>(bias);
    const f32x4* wsb4  = reinterpret_cast<const f32x4*>(wsb);
    f32x4* orow = reinterpret_cast<f32x4*>(out) + (size_t)xrow * (OUT_DIM / 4);
    #pragma unroll
    for (int k = 0; k < 8; ++k) {
        const int i = lane + (k << 6);
        const f32x4 bi = bias4[i];             // L1-resident broadcast
        const f32x4 wv = wsb4[i];
        f32x4 o;
        o.x = fmaf(xs, bi.x, wv.x);
        o.y = fmaf(xs, bi.y, wv.y);
        o.z = fmaf(xs, bi.z, wv.z);
        o.w = fmaf(xs, bi.w, wv.w);
        orow[i] = o;
    }
}

extern "C" void kernel_launch(void* const* d_in, const int* in_sizes, int n_in,
                              void* d_out, int out_size, void* d_ws, size_t ws_size,
                              hipStream_t stream) {
    const float* x    = (const float*)d_in[0];   // [8192, 2048]
    const float* w    = (const float*)d_in[1];   // [2048, 2048]
    const float* bias = (const float*)d_in[2];   // [2048]
    float* out = (float*)d_out;                  // [8192, 2048]
    float* wsb = (float*)d_ws;                   // 2048 floats

    // reset sentinel every call (graph-capture-legal)
    hipMemsetAsync(wsb, 0xFF, OUT_DIM * sizeof(float), stream);

    fused_all<<<NBLK, 256, 0, stream>>>(x, w, bias, out, wsb);
}

// Round 12
// 42.486 us; speedup vs baseline: 1.4829x; 1.4829x over previous
//
#include <hip/hip_runtime.h>

// out[b,o] = (rowsum(x)[b] + rowsum(w)[o]) * bias[o]
// B=8192, IN=2048, OUT=2048, all float32.
//
// ONE fused kernel + tiny sentinel memset. Sync ladder lessons:
//  R5/R8/R9: same-line atomic RMW arrivals serialize (~30ns each) -> never.
//  R8: per-thread agent fences = cache-op storm -> never.
//  R10: 512 blocks = 8 waves/CU starves the READ phases (2.75 TB/s).
//  R11: full occupancy BUT every block re-scanning 8 KB of wsb with
//       uncached agent loads per retry = IC request storm (63 us).
// R12: full occupancy + single AGGREGATOR wave + 1-word flag poll:
//  - 2048 blocks x 256 @ __launch_bounds__(256,8): exact-fit co-residency
//    (validated: R11 completed, incl. rocprof replays; deadlock-free since
//    every block publishes its w-row before any wait).
//  - wave 0 of each block: reduce w-row blk, publish via relaxed agent store.
//  - every wave: reduce its x-row (64 MiB stream hides producer window).
//  - block 0 wave 1: after its x-row, sweep wsb (coalesced agent loads)
//    until no sentinel, then clear flag (1 word).
//  - all other waves: poll flag only (first check free, then s_sleep backoff)
//    -> ~1 uncached load/wave/us instead of 8 KB/block/retry.
//  - phase 3: plain cached reads of wsb/bias (safe: dispatch-start invalidate;
//    in-kernel lines only from post-flag loads), stream out rows.

#define B_DIM 8192
#define IN_DIM 2048
#define OUT_DIM 2048
#define NBLK 2048
#define SENT 0xFFFFFFFFu

typedef float f32x4 __attribute__((ext_vector_type(4)));

__device__ __forceinline__ float butterfly_reduce(float s) {
    #pragma unroll
    for (int off = 32; off; off >>= 1)
        s += __shfl_xor(s, off, 64);
    return s;   // result in all 64 lanes
}

__device__ __forceinline__ float row_reduce(const float* __restrict__ row, int lane) {
    const f32x4* r4 = reinterpret_cast<const f32x4*>(row);
    f32x4 v[8];
    #pragma unroll
    for (int k = 0; k < 8; ++k)
        v[k] = r4[lane + (k << 6)];
    float s = 0.f;
    #pragma unroll
    for (int k = 0; k < 8; ++k)
        s += (v[k].x + v[k].y) + (v[k].z + v[k].w);
    return butterfly_reduce(s);
}

__global__ __launch_bounds__(256, 8) void fused_all(const float* __restrict__ x,
                                                    const float* __restrict__ w,
                                                    const float* __restrict__ bias,
                                                    float* __restrict__ out,
                                                    float* __restrict__ wsb,
                                                    unsigned int* __restrict__ flag) {
    const int tid  = threadIdx.x;
    const int wave = tid >> 6;
    const int lane = tid & 63;
    const int blk  = blockIdx.x;               // 0 .. 2047

    // ---- phase 1: wave 0 reduces w-row `blk`, publishes write-through ----
    if (wave == 0) {
        float s = row_reduce(w + (size_t)blk * IN_DIM, lane);
        if (lane == 0)
            __hip_atomic_store(&wsb[blk], s * bias[blk],
                               __ATOMIC_RELAXED, __HIP_MEMORY_SCOPE_AGENT);
    }

    // ---- phase 2: each wave reduces one x-row ----
    const int xrow = (blk << 2) + wave;        // 0 .. 8191
    const float xs = row_reduce(x + (size_t)xrow * IN_DIM, lane);

    // ---- sync ----
    if (blk == 0 && wave == 1) {
        // aggregator: sweep all 2048 wsb words (coalesced across 64 lanes)
        const unsigned* wu = reinterpret_cast<const unsigned*>(wsb);
        int done;
        do {
            done = 1;
            #pragma unroll
            for (int m = 0; m < 32; ++m) {
                unsigned u = __hip_atomic_load(&wu[lane + (m << 6)],
                                               __ATOMIC_RELAXED,
                                               __HIP_MEMORY_SCOPE_AGENT);
                done &= (u != SENT);
            }
        } while (!__all(done));
        if (lane == 0)
            __hip_atomic_store(flag, 0u, __ATOMIC_RELAXED,
                               __HIP_MEMORY_SCOPE_AGENT);
    } else {
        // 1-word poll; first check free (expected already-done), then backoff
        while (__hip_atomic_load(flag, __ATOMIC_RELAXED,
                                 __HIP_MEMORY_SCOPE_AGENT) == SENT)
            __builtin_amdgcn_s_sleep(32);
    }

    // ---- phase 3: each wave writes its out-row ----
    const f32x4* bias4 = reinterpret_cast<const f32x4*>(bias);
    const f32x4* wsb4  = reinterpret_cast<const f32x4*>(wsb);
    f32x4* orow = reinterpret_cast<f32x4*>(out) + (size_t)xrow * (OUT_DIM / 4);
    #pragma unroll
    for (int k = 0; k < 8; ++k) {
        const int i = lane + (k << 6);
        const f32x4 bi = bias4[i];             // L1-resident broadcast
        const f32x4 wv = wsb4[i];
        f32x4 o;
        o.x = fmaf(xs, bi.x, wv.x);
        o.y = fmaf(xs, bi.y, wv.y);
        o.z = fmaf(xs, bi.z, wv.z);
        o.w = fmaf(xs, bi.w, wv.w);
        orow[i] = o;
    }
}

extern "C" void kernel_launch(void* const* d_in, const int* in_sizes, int n_in,
                              void* d_out, int out_size, void* d_ws, size_t ws_size,
                              hipStream_t stream) {
    const float* x    = (const float*)d_in[0];   // [8192, 2048]
    const float* w    = (const float*)d_in[1];   // [2048, 2048]
    const float* bias = (const float*)d_in[2];   // [2048]
    float* out = (float*)d_out;                  // [8192, 2048]
    float* wsb = (float*)d_ws;                   // 2048 floats
    unsigned int* flag = (unsigned int*)((char*)d_ws + OUT_DIM * sizeof(float));

    // reset wsb sentinels + flag (0xFFFFFFFF) every call (graph-capture-legal)
    hipMemsetAsync(d_ws, 0xFF, OUT_DIM * sizeof(float) + 64, stream);

    fused_all<<<NBLK, 256, 0, stream>>>(x, w, bias, out, wsb, flag);
}

// Round 13
// 30.901 us; speedup vs baseline: 2.0389x; 1.3749x over previous
//
#include <hip/hip_runtime.h>

// out[b,o] = (rowsum(x)[b] + rowsum(w)[o]) * bias[o]
// B=8192, IN=2048, OUT=2048, all float32.
//
// Two kernels (fused single-kernel arc R4-R12 abandoned: every global-sync
// design costs >=10us on 8 XCDs — RMW serialization, fence storms, or
// poll-traffic storms — exceeding the ~2-4us boundary it removes).
//
// K1 (pure read, 80 MiB): TWO rows per wave, all 16 loads issued before
//   either reduce -> 2x loads-in-flight per wave vs R7 (read phase measured
//   ~4.7 TB/s there; writes hit 6.65 — reads need deeper latency hiding).
// K2 (pure write, 64 MiB): R7's register-stationary writer, unchanged.

#define B_DIM 8192
#define IN_DIM 2048
#define OUT_DIM 2048

typedef float f32x4 __attribute__((ext_vector_type(4)));

__device__ __forceinline__ float butterfly_reduce(float s) {
    #pragma unroll
    for (int off = 32; off; off >>= 1)
        s += __shfl_xor(s, off, 64);
    return s;   // result in all 64 lanes
}

// 1280 blocks x 256 (5120 waves): wave wid owns rows 2*wid, 2*wid+1 of the
// concatenated [x (8192 rows); w (2048 rows)] space. Never straddles x/w.
__global__ __launch_bounds__(256) void rowsum2_kernel(const float* __restrict__ x,
                                                      const float* __restrict__ w,
                                                      const float* __restrict__ bias,
                                                      float* __restrict__ xsum,
                                                      float* __restrict__ wsb) {
    const int wid  = (blockIdx.x << 2) + (threadIdx.x >> 6);   // 0 .. 5119
    const int lane = threadIdx.x & 63;
    const int r0   = wid << 1;                                  // 0 .. 10238
    const bool is_x = (r0 < B_DIM);
    const float* base = is_x ? (x + (size_t)r0 * IN_DIM)
                             : (w + (size_t)(r0 - B_DIM) * IN_DIM);
    const f32x4* a4 = reinterpret_cast<const f32x4*>(base);
    const f32x4* b4 = reinterpret_cast<const f32x4*>(base + IN_DIM);

    // issue ALL 16 loads before any reduce (32 KB in flight per wave)
    f32x4 va[8], vb[8];
    #pragma unroll
    for (int k = 0; k < 8; ++k) va[k] = a4[lane + (k << 6)];
    #pragma unroll
    for (int k = 0; k < 8; ++k) vb[k] = b4[lane + (k << 6)];

    // two independent reduce trees (ILP)
    float sa = 0.f, sb = 0.f;
    #pragma unroll
    for (int k = 0; k < 8; ++k) {
        sa += (va[k].x + va[k].y) + (va[k].z + va[k].w);
        sb += (vb[k].x + vb[k].y) + (vb[k].z + vb[k].w);
    }
    #pragma unroll
    for (int off = 32; off; off >>= 1) {
        sa += __shfl_xor(sa, off, 64);
        sb += __shfl_xor(sb, off, 64);
    }

    if (lane == 0) {
        if (is_x) {
            xsum[r0]     = sa;
            xsum[r0 + 1] = sb;
        } else {
            const int o = r0 - B_DIM;
            wsb[o]     = sa * bias[o];
            wsb[o + 1] = sb * bias[o + 1];
        }
    }
}

// 2048 blocks x 256: block covers all 2048 cols (bias/wsb in 16 VGPRs,
// loaded once), writes 4 consecutive rows. Unchanged from R7.
__global__ __launch_bounds__(256) void write_kernel(const float* __restrict__ xsum,
                                                    const float* __restrict__ bias,
                                                    const float* __restrict__ wsb,
                                                    f32x4* __restrict__ out4) {
    const int tid   = threadIdx.x;
    const int rbase = blockIdx.x << 2;                   // 4 rows per block
    const f32x4* bias4 = reinterpret_cast<const f32x4*>(bias);
    const f32x4* wsb4  = reinterpret_cast<const f32x4*>(wsb);

    const f32x4 b0 = bias4[tid];
    const f32x4 b1 = bias4[tid + 256];
    const f32x4 w0 = wsb4[tid];
    const f32x4 w1 = wsb4[tid + 256];

    const f32x4 xs4 = *reinterpret_cast<const f32x4*>(&xsum[rbase]);

    #pragma unroll
    for (int r = 0; r < 4; ++r) {
        const float xs = xs4[r];
        f32x4* orow = out4 + (size_t)(rbase + r) * (OUT_DIM / 4);
        f32x4 o0, o1;
        o0.x = fmaf(xs, b0.x, w0.x);
        o0.y = fmaf(xs, b0.y, w0.y);
        o0.z = fmaf(xs, b0.z, w0.z);
        o0.w = fmaf(xs, b0.w, w0.w);
        o1.x = fmaf(xs, b1.x, w1.x);
        o1.y = fmaf(xs, b1.y, w1.y);
        o1.z = fmaf(xs, b1.z, w1.z);
        o1.w = fmaf(xs, b1.w, w1.w);
        orow[tid]       = o0;
        orow[tid + 256] = o1;
    }
}

extern "C" void kernel_launch(void* const* d_in, const int* in_sizes, int n_in,
                              void* d_out, int out_size, void* d_ws, size_t ws_size,
                              hipStream_t stream) {
    const float* x    = (const float*)d_in[0];   // [8192, 2048]
    const float* w    = (const float*)d_in[1];   // [2048, 2048]
    const float* bias = (const float*)d_in[2];   // [2048]
    float* out  = (float*)d_out;                 // [8192, 2048]
    float* xsum = (float*)d_ws;                  // 8192 floats
    float* wsb  = xsum + B_DIM;                  // 2048 floats

    rowsum2_kernel<<<(B_DIM + OUT_DIM) / 8, 256, 0, stream>>>(x, w, bias, xsum, wsb);
    write_kernel<<<B_DIM / 4, 256, 0, stream>>>(xsum, bias, wsb, (f32x4*)out);
}

// Round 14
// 29.943 us; speedup vs baseline: 2.1042x; 1.0320x over previous
//
#include <hip/hip_runtime.h>

// out[b,o] = (rowsum(x)[b] + rowsum(w)[o]) * bias[o]
// B=8192, IN=2048, OUT=2048, all float32.
//
// Two kernels (fused/global-sync arc R4-R12: every sync design >= 10us on
// 8 XCDs; abandoned). R14 targets K1's measured ~5 TB/s read rate: the
// per-row cross-lane butterfly tail (6 serialized ds_bpermute + vmcnt-all
// gate + lane0 store per 8KB row) is removed from the hot x-path:
//   K1: x rows -> PER-LANE partials xpart[row][64] (coalesced 256B store,
//       zero cross-lane ops, streaming); w rows (20%) -> old butterfly wsb.
//   K2: prologue: each wave butterflies 64 partials of one row (1 load,
//       amortized over 8KB of writes), then R7's register-stationary writer.

#define B_DIM 8192
#define IN_DIM 2048
#define OUT_DIM 2048

typedef float f32x4 __attribute__((ext_vector_type(4)));

__device__ __forceinline__ float butterfly_reduce(float s) {
    #pragma unroll
    for (int off = 32; off; off >>= 1)
        s += __shfl_xor(s, off, 64);
    return s;   // result in all 64 lanes
}

// 2560 blocks x 256 (10240 waves): waves 0..8191 -> x rows (partial store),
// waves 8192..10239 -> w rows (full butterfly into wsb).
__global__ __launch_bounds__(256) void rowsum_kernel(const float* __restrict__ x,
                                                     const float* __restrict__ w,
                                                     const float* __restrict__ bias,
                                                     float* __restrict__ xpart,
                                                     float* __restrict__ wsb) {
    const int wid  = (blockIdx.x << 2) + (threadIdx.x >> 6);   // 0 .. 10239
    const int lane = threadIdx.x & 63;

    if (wid < B_DIM) {
        // x-path: per-lane strided partial, NO cross-lane ops, no vmcnt-all gate
        const f32x4* r4 = reinterpret_cast<const f32x4*>(x + (size_t)wid * IN_DIM);
        float s = 0.f;
        #pragma unroll
        for (int k = 0; k < 8; ++k) {
            const f32x4 v = r4[lane + (k << 6)];
            s += (v.x + v.y) + (v.z + v.w);    // each add waits only its own load
        }
        xpart[(wid << 6) | lane] = s;          // coalesced 256 B per row
    } else {
        // w-path (20% of rows): classic butterfly into wsb
        const int o = wid - B_DIM;             // 0 .. 2047
        const f32x4* r4 = reinterpret_cast<const f32x4*>(w + (size_t)o * IN_DIM);
        float s = 0.f;
        #pragma unroll
        for (int k = 0; k < 8; ++k) {
            const f32x4 v = r4[lane + (k << 6)];
            s += (v.x + v.y) + (v.z + v.w);
        }
        s = butterfly_reduce(s);
        if (lane == 0)
            wsb[o] = s * bias[o];
    }
}

// 2048 blocks x 256: prologue reduces 4 rows' partials (one butterfly per
// wave, amortized over 8 KB of writes), then R7's register-stationary writer.
__global__ __launch_bounds__(256) void write_kernel(const float* __restrict__ xpart,
                                                    const float* __restrict__ bias,
                                                    const float* __restrict__ wsb,
                                                    f32x4* __restrict__ out4) {
    const int tid   = threadIdx.x;
    const int wave  = tid >> 6;
    const int lane  = tid & 63;
    const int rbase = blockIdx.x << 2;                   // 4 rows per block
    const f32x4* bias4 = reinterpret_cast<const f32x4*>(bias);
    const f32x4* wsb4  = reinterpret_cast<const f32x4*>(wsb);

    // issue column-stationary loads first (independent of prologue)
    const f32x4 b0 = bias4[tid];
    const f32x4 b1 = bias4[tid + 256];
    const f32x4 w0 = wsb4[tid];
    const f32x4 w1 = wsb4[tid + 256];

    // prologue: wave r reduces row (rbase+r)'s 64 partials
    __shared__ float ls[4];
    float p = xpart[((rbase + wave) << 6) | lane];
    p = butterfly_reduce(p);
    if (lane == 0) ls[wave] = p;
    __syncthreads();

    const f32x4 xs4 = { ls[0], ls[1], ls[2], ls[3] };

    #pragma unroll
    for (int r = 0; r < 4; ++r) {
        const float xs = xs4[r];
        f32x4* orow = out4 + (size_t)(rbase + r) * (OUT_DIM / 4);
        f32x4 o0, o1;
        o0.x = fmaf(xs, b0.x, w0.x);
        o0.y = fmaf(xs, b0.y, w0.y);
        o0.z = fmaf(xs, b0.z, w0.z);
        o0.w = fmaf(xs, b0.w, w0.w);
        o1.x = fmaf(xs, b1.x, w1.x);
        o1.y = fmaf(xs, b1.y, w1.y);
        o1.z = fmaf(xs, b1.z, w1.z);
        o1.w = fmaf(xs, b1.w, w1.w);
        orow[tid]       = o0;
        orow[tid + 256] = o1;
    }
}

extern "C" void kernel_launch(void* const* d_in, const int* in_sizes, int n_in,
                              void* d_out, int out_size, void* d_ws, size_t ws_size,
                              hipStream_t stream) {
    const float* x    = (const float*)d_in[0];   // [8192, 2048]
    const float* w    = (const float*)d_in[1];   // [2048, 2048]
    const float* bias = (const float*)d_in[2];   // [2048]
    float* out   = (float*)d_out;                // [8192, 2048]
    float* xpart = (float*)d_ws;                 // [8192][64] floats = 2 MiB
    float* wsb   = xpart + (size_t)B_DIM * 64;   // 2048 floats

    rowsum_kernel<<<(B_DIM + OUT_DIM) / 4, 256, 0, stream>>>(x, w, bias, xpart, wsb);
    write_kernel<<<B_DIM / 4, 256, 0, stream>>>(xpart, bias, wsb, (f32x4*)out);
}